// Round 2
// baseline (224.942 us; speedup 1.0000x reference)
//
#include <hip/hip_runtime.h>
#include <cstdint>

// BinarizedLeNet5 / CIFAR10, B=2048.  Round 4.
//  k1 : back to round-2 geometry (grid 2048, thread = 1 pooled pixel, in[48])
//       PLUS (a) explicit double-buffered weight prefetch (channel o+1's 28
//       floats + bnp load issued before channel o's 108-FMA block) and
//       (b) wave-staggered channel rotation (wave w starts at channel 8w) to
//       break the all-waves-lockstep lgkmcnt stall. Per-channel float op order
//       unchanged -> exact.
//  k0/k3/k4/k56 unchanged from round 3.

#define BSZ 2048

__device__ __forceinline__ float sgnf(float w) {
    return (w > 0.f) ? 1.f : ((w < 0.f) ? -1.f : 0.f);
}

// ---------------- k0: all packing ----------------
__global__ __launch_bounds__(256) void k0_pack(
    const float* __restrict__ c1w, const float* __restrict__ c2w,
    const float* __restrict__ f1w, const float* __restrict__ f2w,
    const float* __restrict__ c1b, const float* __restrict__ c2b,
    const float* __restrict__ f1b, const float* __restrict__ f2b,
    const float* __restrict__ b1g, const float* __restrict__ b1b,
    const float* __restrict__ b1m, const float* __restrict__ b1v,
    const float* __restrict__ b2g, const float* __restrict__ b2b,
    const float* __restrict__ b2m, const float* __restrict__ b2v,
    const float* __restrict__ b3g, const float* __restrict__ b3b,
    const float* __restrict__ b3m, const float* __restrict__ b3v,
    const float* __restrict__ b4g, const float* __restrict__ b4b,
    const float* __restrict__ b4m, const float* __restrict__ b4v,
    float* __restrict__ sw1, uint32_t* __restrict__ wp2,
    uint32_t* __restrict__ wpf1, uint32_t* __restrict__ wpf2,
    float* __restrict__ bnp1, float* __restrict__ bnp2,
    float* __restrict__ bnp3, float* __restrict__ bnp4) {
    int bid = blockIdx.x, t = threadIdx.x;
    if (bid < 1024) {
        // fc1 pack: wave W covers 512 consecutive elements of row o.
        int W = bid * 4 + (t >> 6), l = t & 63;
        int o = W >> 3, chunk = W & 7;
        const float* row = f1w + (size_t)o * 4096 + chunk * 512;
        int kwb = chunk * 16;
#pragma unroll
        for (int j = 0; j < 8; j++) {
            float vj = row[j * 64 + l];
            unsigned long long mk = __ballot(vj > 0.f);
            if (l == 0) {
                wpf1[(size_t)(kwb + 2 * j) * 512 + o] = (uint32_t)mk;
                wpf1[(size_t)(kwb + 2 * j + 1) * 512 + o] = (uint32_t)(mk >> 32);
            }
        }
    } else if (bid == 1024) {
        // conv2 pack: wp2[o*16+k]: k<9 = weight bits, k=9..15 = precomputed
        // border-correction constants {R0,R2,C0,C2,t0,t2,(t6|t8<<16)}.
        __shared__ uint32_t wloc[576];
        for (int i = t; i < 576; i += 256) {
            int o = i / 9, k = i - o * 9;
            uint32_t word = 0;
            for (int c = 0; c < 32; c++)
                if (c2w[(o * 32 + c) * 9 + k] > 0.f) word |= (1u << c);
            wloc[i] = word;
        }
        __syncthreads();
        for (int i = t; i < 1024; i += 256) {
            int o = i >> 4, k = i & 15;
            const uint32_t* wr = wloc + o * 9;
            uint32_t outv;
            if (k < 9) {
                outv = wr[k];
            } else {
                int tv[9];
#pragma unroll
                for (int j = 0; j < 9; j++) tv[j] = 32 - 2 * __popc(wr[j]);
                int v = 0;
                if (k == 9)  v = tv[0] + tv[1] + tv[2];            // R0
                if (k == 10) v = tv[6] + tv[7] + tv[8];            // R2
                if (k == 11) v = tv[0] + tv[3] + tv[6];            // C0
                if (k == 12) v = tv[2] + tv[5] + tv[8];            // C2
                if (k == 13) v = tv[0];                            // t0
                if (k == 14) v = tv[2];                            // t2
                if (k == 15)
                    v = (int)(((uint32_t)(uint16_t)tv[6]) |
                              ((uint32_t)(uint16_t)tv[8] << 16));  // t6|t8
                outv = (uint32_t)v;
            }
            wp2[i] = outv;
        }
        if (t < 64) {
            float inv = __fdiv_rn(b2g[t], __fsqrt_rn(b2v[t] + 1e-5f));
            float add = __fsub_rn(b2b[t], __fmul_rn(b2m[t], inv));
            bnp2[t * 4] = inv; bnp2[t * 4 + 1] = add;
            bnp2[t * 4 + 2] = c2b[t]; bnp2[t * 4 + 3] = 0.f;
        }
    } else if (bid == 1025) {
        // conv1 signed weights (stride-32 rows) + bn1 params.
        for (int i = t; i < 1024; i += 256) {
            int o = i >> 5, r = i & 31;
            sw1[i] = (r < 27) ? sgnf(c1w[o * 27 + r]) : 0.f;
        }
        if (t < 32) {
            float inv = __fdiv_rn(b1g[t], __fsqrt_rn(b1v[t] + 1e-5f));
            float add = __fsub_rn(b1b[t], __fmul_rn(b1m[t], inv));
            bnp1[t * 4] = inv; bnp1[t * 4 + 1] = add;
            bnp1[t * 4 + 2] = c1b[t]; bnp1[t * 4 + 3] = 0.f;
        }
    } else if (bid < 1042) {
        // fc2 pack: wpf2[k*256+o]
        int i = (bid - 1026) * 256 + t;       // 4096 = [16 k][256 o]
        int k = i >> 8, o = i & 255;
        const float* r = f2w + (size_t)o * 512 + k * 32;
        uint32_t word = 0;
#pragma unroll
        for (int j = 0; j < 32; j++)
            if (r[j] > 0.f) word |= (1u << j);
        wpf2[k * 256 + o] = word;
    } else {
        // bn3 + bn4 params (with fc biases folded in slot .z)
        for (int i = t; i < 512; i += 256) {
            float inv = __fdiv_rn(b3g[i], __fsqrt_rn(b3v[i] + 1e-5f));
            float add = __fsub_rn(b3b[i], __fmul_rn(b3m[i], inv));
            bnp3[i * 4] = inv; bnp3[i * 4 + 1] = add;
            bnp3[i * 4 + 2] = f1b[i]; bnp3[i * 4 + 3] = 0.f;
        }
        if (t < 256) {
            float inv = __fdiv_rn(b4g[t], __fsqrt_rn(b4v[t] + 1e-5f));
            float add = __fsub_rn(b4b[t], __fmul_rn(b4m[t], inv));
            bnp4[t * 4] = inv; bnp4[t * 4 + 1] = add;
            bnp4[t * 4 + 2] = f2b[t]; bnp4[t * 4 + 3] = 0.f;
        }
    }
}

// ---------------- k1: conv1 + pool + bn1 + sign-pack ----------------
// grid 2048, thread = 1 pooled pixel (4x4 patch). Double-buffered scalar
// weight prefetch + wave-staggered channel rotation.
__global__ __launch_bounds__(256) void k1_conv1(
    const float* __restrict__ x, const float* __restrict__ sw,
    const float* __restrict__ bnp, uint32_t* __restrict__ out) {
    int b = blockIdx.x, t = threadIdx.x;
    int py = t >> 4, px = t & 15;
    int y0 = 2 * py - 1, x0 = 2 * px - 1;
    float in[48];
#pragma unroll
    for (int c = 0; c < 3; c++) {
        const float* xc = x + ((size_t)b * 3 + c) * 1024;
#pragma unroll
        for (int i = 0; i < 4; i++) {
            int yy = y0 + i;
            bool ry = (unsigned)yy < 32u;
#pragma unroll
            for (int j = 0; j < 4; j++) {
                int xx = x0 + j;
                in[c * 16 + i * 4 + j] =
                    (ry && (unsigned)xx < 32u) ? xc[yy * 32 + xx] : 0.f;
            }
        }
    }
    // wave-staggered start channel (scalar), double-buffered weight regs
    int o = __builtin_amdgcn_readfirstlane((threadIdx.x >> 6) << 3);
    float cw[28];
    {
        const float4* wr = (const float4*)(sw + (o << 5));
#pragma unroll
        for (int j = 0; j < 7; j++) ((float4*)cw)[j] = wr[j];
    }
    float4 pc = ((const float4*)bnp)[o];
    uint32_t word = 0;
#pragma unroll 1
    for (int i = 0; i < 32; i++) {
        int on = (o + 1) & 31;
        float nw[28];
        {
            const float4* wrn = (const float4*)(sw + (on << 5));
#pragma unroll
            for (int j = 0; j < 7; j++) ((float4*)nw)[j] = wrn[j];
        }
        float4 pn = ((const float4*)bnp)[on];
        float a00 = 0.f, a01 = 0.f, a10 = 0.f, a11 = 0.f;
#pragma unroll
        for (int c = 0; c < 3; c++)
#pragma unroll
            for (int ky = 0; ky < 3; ky++)
#pragma unroll
                for (int kx = 0; kx < 3; kx++) {
                    float wv = cw[c * 9 + ky * 3 + kx];
                    a00 = fmaf(in[c * 16 + ky * 4 + kx], wv, a00);
                    a01 = fmaf(in[c * 16 + ky * 4 + kx + 1], wv, a01);
                    a10 = fmaf(in[c * 16 + (ky + 1) * 4 + kx], wv, a10);
                    a11 = fmaf(in[c * 16 + (ky + 1) * 4 + kx + 1], wv, a11);
                }
        float mx = fmaxf(fmaxf(a00, a01), fmaxf(a10, a11));
        float h = __fadd_rn(mx, pc.z);
        float val = __fadd_rn(__fmul_rn(h, pc.x), pc.y);
        word |= (val > 0.f) ? (1u << o) : 0u;
#pragma unroll
        for (int j = 0; j < 7; j++) ((float4*)cw)[j] = ((const float4*)nw)[j];
        pc = pn;
        o = on;
    }
    out[(size_t)b * 256 + t] = word;
}

// ---------------- k3: conv2 xnor-popc + pool + bn2 + sign-pack ----------------
// 2 samples / block; per-channel: one s_load_dwordx16 row (weights + precomputed
// corrections), then 2 samples' worth of xor/popc per fetch.
__device__ __forceinline__ int conv2_mi(
    const uint32_t* val,
    uint32_t w0, uint32_t w1, uint32_t w2, uint32_t w3, uint32_t w4,
    uint32_t w5, uint32_t w6, uint32_t w7, uint32_t w8,
    int R0, int R2, int C0, int C2, int t0, int t2, int t6, int t8,
    bool top, bool bot, bool lef, bool rig,
    bool ctl, bool ctr, bool cbl, bool cbr) {
    int P00 = __popc(val[0] ^ w0) + __popc(val[1] ^ w1) + __popc(val[2] ^ w2) +
              __popc(val[4] ^ w3) + __popc(val[5] ^ w4) + __popc(val[6] ^ w5) +
              __popc(val[8] ^ w6) + __popc(val[9] ^ w7) + __popc(val[10] ^ w8);
    int P01 = __popc(val[1] ^ w0) + __popc(val[2] ^ w1) + __popc(val[3] ^ w2) +
              __popc(val[5] ^ w3) + __popc(val[6] ^ w4) + __popc(val[7] ^ w5) +
              __popc(val[9] ^ w6) + __popc(val[10] ^ w7) + __popc(val[11] ^ w8);
    int P10 = __popc(val[4] ^ w0) + __popc(val[5] ^ w1) + __popc(val[6] ^ w2) +
              __popc(val[8] ^ w3) + __popc(val[9] ^ w4) + __popc(val[10] ^ w5) +
              __popc(val[12] ^ w6) + __popc(val[13] ^ w7) + __popc(val[14] ^ w8);
    int P11 = __popc(val[5] ^ w0) + __popc(val[6] ^ w1) + __popc(val[7] ^ w2) +
              __popc(val[9] ^ w3) + __popc(val[10] ^ w4) + __popc(val[11] ^ w5) +
              __popc(val[13] ^ w6) + __popc(val[14] ^ w7) + __popc(val[15] ^ w8);
    int s00 = 288 - 2 * P00 - ((top ? R0 : 0) + (lef ? C0 : 0) - (ctl ? t0 : 0));
    int s01 = 288 - 2 * P01 - ((top ? R0 : 0) + (rig ? C2 : 0) - (ctr ? t2 : 0));
    int s10 = 288 - 2 * P10 - ((bot ? R2 : 0) + (lef ? C0 : 0) - (cbl ? t6 : 0));
    int s11 = 288 - 2 * P11 - ((bot ? R2 : 0) + (rig ? C2 : 0) - (cbr ? t8 : 0));
    return max(max(s00, s01), max(s10, s11));
}

__global__ __launch_bounds__(256) void k3_conv2(
    const uint32_t* __restrict__ in, const uint32_t* __restrict__ wp,
    const float* __restrict__ bnp, uint32_t* __restrict__ out) {
    int t = threadIdx.x;
    int b0 = blockIdx.x * 2;
    const int P = 19;
    __shared__ uint32_t tile[2][18 * 19];
    uint32_t* tf = &tile[0][0];
    for (int i = t; i < 2 * 18 * 19; i += 256) tf[i] = 0;
    __syncthreads();
    {
        int y = t >> 4, xx = t & 15;
#pragma unroll
        for (int s = 0; s < 2; s++)
            tile[s][(y + 1) * P + xx + 1] = in[(size_t)(b0 + s) * 256 + t];
    }
    __syncthreads();
    int wv = t >> 6, l = t & 63;
    int py = l >> 3, px = l & 7;
    uint32_t va[16], vb[16];
#pragma unroll
    for (int i = 0; i < 4; i++)
#pragma unroll
        for (int j = 0; j < 4; j++) {
            va[i * 4 + j] = tile[0][(2 * py + i) * P + 2 * px + j];
            vb[i * 4 + j] = tile[1][(2 * py + i) * P + 2 * px + j];
        }
    bool top = (py == 0), bot = (py == 7), lef = (px == 0), rig = (px == 7);
    bool ctl = top && lef, ctr = top && rig, cbl = bot && lef, cbr = bot && rig;
#pragma unroll 2
    for (int oi = 0; oi < 16; oi++) {
        int o = __builtin_amdgcn_readfirstlane(wv * 16 + oi);  // force SGPR
        const uint32_t* wo = wp + o * 16;
        uint32_t w0 = wo[0], w1 = wo[1], w2 = wo[2], w3 = wo[3], w4 = wo[4],
                 w5 = wo[5], w6 = wo[6], w7 = wo[7], w8 = wo[8];
        int R0 = (int)wo[9], R2 = (int)wo[10], C0 = (int)wo[11], C2 = (int)wo[12];
        int t0 = (int)wo[13], t2 = (int)wo[14];
        int pk = (int)wo[15];
        int t6 = (int)(short)(pk & 0xffff);
        int t8 = pk >> 16;
        float4 p = ((const float4*)bnp)[o];   // SGPR-indexed -> s_load
        int miA = conv2_mi(va, w0, w1, w2, w3, w4, w5, w6, w7, w8,
                           R0, R2, C0, C2, t0, t2, t6, t8,
                           top, bot, lef, rig, ctl, ctr, cbl, cbr);
        float hA = __fadd_rn((float)miA, p.z);
        float bvA = __fadd_rn(__fmul_rn(hA, p.x), p.y);
        unsigned long long mkA = __ballot(bvA > 0.f);
        int miB = conv2_mi(vb, w0, w1, w2, w3, w4, w5, w6, w7, w8,
                           R0, R2, C0, C2, t0, t2, t6, t8,
                           top, bot, lef, rig, ctl, ctr, cbl, cbr);
        float hB = __fadd_rn((float)miB, p.z);
        float bvB = __fadd_rn(__fmul_rn(hB, p.x), p.y);
        unsigned long long mkB = __ballot(bvB > 0.f);
        if (l == 0) {
            *(uint2*)(out + (size_t)b0 * 128 + 2 * o) =
                make_uint2((uint32_t)mkA, (uint32_t)(mkA >> 32));
            *(uint2*)(out + (size_t)(b0 + 1) * 128 + 2 * o) =
                make_uint2((uint32_t)mkB, (uint32_t)(mkB >> 32));
        }
    }
}

// ---------------- k4: fc1 xnor-popc + bn3 + sign-pack ----------------
__global__ __launch_bounds__(256) void k4_fc1(
    const uint32_t* __restrict__ in, const uint32_t* __restrict__ wp,
    const float* __restrict__ bnp, uint32_t* __restrict__ out) {
    int t = threadIdx.x;
    int half = blockIdx.x & 1, bg = blockIdx.x >> 1;
    int b0 = bg * 4;
    int wv = t >> 6, l = t & 63;
    int obase = half * 256 + wv * 64;
    int o = obase + l;
    float4 p = ((const float4*)bnp)[o];          // per-lane, coalesced
    const uint32_t* s0 = in + (size_t)b0 * 128;  // uniform -> s_load
    int a0 = 0, a1 = 0, a2 = 0, a3 = 0;
#pragma unroll 8
    for (int k = 0; k < 128; k++) {
        uint32_t w = wp[k * 512 + o];            // coalesced vector load
        a0 += __popc(w ^ s0[k]);
        a1 += __popc(w ^ s0[128 + k]);
        a2 += __popc(w ^ s0[256 + k]);
        a3 += __popc(w ^ s0[384 + k]);
    }
    int word_idx = obase >> 5;
    int accs[4] = {a0, a1, a2, a3};
#pragma unroll
    for (int nb = 0; nb < 4; nb++) {
        float h = __fadd_rn((float)(4096 - 2 * accs[nb]), p.z);
        float bv = __fadd_rn(__fmul_rn(h, p.x), p.y);
        unsigned long long mk = __ballot(bv > 0.f);
        if (l == 0) {
            out[(size_t)(b0 + nb) * 16 + word_idx] = (uint32_t)mk;
            out[(size_t)(b0 + nb) * 16 + word_idx + 1] = (uint32_t)(mk >> 32);
        }
    }
}

// ---------------- k56: fc2 + bn4 + clip + fc3 + log_softmax ----------------
__global__ __launch_bounds__(256) void k56_fc23(
    const uint32_t* __restrict__ in, const uint32_t* __restrict__ wp,
    const float* __restrict__ bnp, const float* __restrict__ f3w,
    const float* __restrict__ f3b, float* __restrict__ out) {
    int b = blockIdx.x, t = threadIdx.x;
    __shared__ uint32_t li[16];
    __shared__ float hbuf[256];
    if (t < 16) li[t] = in[(size_t)b * 16 + t];
    __syncthreads();
    int acc = 0;
#pragma unroll
    for (int k = 0; k < 16; k++) acc += __popc(wp[k * 256 + t] ^ li[k]);
    float4 p = ((const float4*)bnp)[t];
    float h = __fadd_rn((float)(512 - 2 * acc), p.z);
    float bv = __fadd_rn(__fmul_rn(h, p.x), p.y);
    bv = fminf(1.f, fmaxf(-1.f, bv));
    hbuf[t] = bv;
    __syncthreads();
    if (t < 64) {
        float4 hv = ((const float4*)hbuf)[t];
        float logits[10];
#pragma unroll
        for (int j = 0; j < 10; j++) {
            const float4* wp4 = (const float4*)(f3w + j * 256);
            float4 w4 = wp4[t];
            float pp = hv.x * w4.x + hv.y * w4.y + hv.z * w4.z + hv.w * w4.w;
#pragma unroll
            for (int off = 32; off > 0; off >>= 1) pp += __shfl_xor(pp, off, 64);
            logits[j] = pp + f3b[j];
        }
        float mx = logits[0];
#pragma unroll
        for (int j = 1; j < 10; j++) mx = fmaxf(mx, logits[j]);
        float sum = 0.f;
#pragma unroll
        for (int j = 0; j < 10; j++) sum += expf(logits[j] - mx);
        float ls = mx + logf(sum);
        if (t < 10) out[(size_t)b * 10 + t] = logits[t] - ls;
    }
}

extern "C" void kernel_launch(void* const* d_in, const int* in_sizes, int n_in,
                              void* d_out, int out_size, void* d_ws, size_t ws_size,
                              hipStream_t stream) {
    (void)in_sizes; (void)n_in; (void)out_size; (void)ws_size;
    const float* x   = (const float*)d_in[0];
    const float* c1w = (const float*)d_in[1];
    const float* c1b = (const float*)d_in[2];
    const float* b1g = (const float*)d_in[3];
    const float* b1b = (const float*)d_in[4];
    const float* b1m = (const float*)d_in[5];
    const float* b1v = (const float*)d_in[6];
    const float* c2w = (const float*)d_in[7];
    const float* c2b = (const float*)d_in[8];
    const float* b2g = (const float*)d_in[9];
    const float* b2b = (const float*)d_in[10];
    const float* b2m = (const float*)d_in[11];
    const float* b2v = (const float*)d_in[12];
    const float* f1w = (const float*)d_in[13];
    const float* f1b = (const float*)d_in[14];
    const float* b3g = (const float*)d_in[15];
    const float* b3b = (const float*)d_in[16];
    const float* b3m = (const float*)d_in[17];
    const float* b3v = (const float*)d_in[18];
    const float* f2w = (const float*)d_in[19];
    const float* f2b = (const float*)d_in[20];
    const float* b4g = (const float*)d_in[21];
    const float* b4b = (const float*)d_in[22];
    const float* b4m = (const float*)d_in[23];
    const float* b4v = (const float*)d_in[24];
    const float* f3w = (const float*)d_in[25];
    const float* f3b = (const float*)d_in[26];
    float* out = (float*)d_out;

    uint8_t* ws = (uint8_t*)d_ws;
    uint32_t* ws1  = (uint32_t*)(ws + 0);         // [B,256] conv2 in bits  2 MB
    uint32_t* ws2  = (uint32_t*)(ws + 2097152);   // [B,128] fc1 in bits    1 MB
    uint32_t* ws3  = (uint32_t*)(ws + 3145728);   // [B,16]  fc2 in bits  128 KB
    float*    sw1  = (float*)   (ws + 3276800);   // [32,32] signed conv1 w
    uint32_t* wp2  = (uint32_t*)(ws + 3280896);   // [64,16] conv2 bits + corr
    uint32_t* wpf1 = (uint32_t*)(ws + 3284992);   // [128,512] fc1 bits^T
    uint32_t* wpf2 = (uint32_t*)(ws + 3547136);   // [16,256]  fc2 bits^T
    float*    bnp1 = (float*)   (ws + 3563520);   // [32]  {inv,add,bias,0}
    float*    bnp2 = (float*)   (ws + 3564032);   // [64]
    float*    bnp3 = (float*)   (ws + 3565056);   // [512]
    float*    bnp4 = (float*)   (ws + 3573248);   // [256]

    k0_pack<<<1043, 256, 0, stream>>>(c1w, c2w, f1w, f2w, c1b, c2b, f1b, f2b,
                                      b1g, b1b, b1m, b1v, b2g, b2b, b2m, b2v,
                                      b3g, b3b, b3m, b3v, b4g, b4b, b4m, b4v,
                                      sw1, wp2, wpf1, wpf2, bnp1, bnp2, bnp3, bnp4);
    k1_conv1<<<BSZ, 256, 0, stream>>>(x, sw1, bnp1, ws1);
    k3_conv2<<<BSZ / 2, 256, 0, stream>>>(ws1, wp2, bnp2, ws2);
    k4_fc1<<<1024, 256, 0, stream>>>(ws2, wpf1, bnp3, ws3);
    k56_fc23<<<BSZ, 256, 0, stream>>>(ws3, wpf2, bnp4, f3w, f3b, out);
}

// Round 4
// 207.193 us; speedup vs baseline: 1.0857x; 1.0857x over previous
//
#include <hip/hip_runtime.h>
#include <cstdint>

// BinarizedLeNet5 / CIFAR10, B=2048.  Round 5 (resubmit — round-3 bench was an
// infra failure: "container failed twice", no counters collected).
//  k1 : round-2 main loop (grid 2048, thread = 1 pooled pixel, 32-channel loop,
//       s_load weights, exact fmaf order) BUT inputs staged through a
//       zero-padded LDS tile (34x36x3, coalesced dwordx4 fill) instead of 48
//       bounds-checked scalar global loads. Kills the VMEM-latency input phase.
//  k56: 4 samples per block (grid 512): wp words reused 4x, softmax phase uses
//       all 4 waves (wave w = sample w). Same per-sample float op order.
//  k0/k3/k4 unchanged from round 4.

#define BSZ 2048

__device__ __forceinline__ float sgnf(float w) {
    return (w > 0.f) ? 1.f : ((w < 0.f) ? -1.f : 0.f);
}

// ---------------- k0: all packing ----------------
__global__ __launch_bounds__(256) void k0_pack(
    const float* __restrict__ c1w, const float* __restrict__ c2w,
    const float* __restrict__ f1w, const float* __restrict__ f2w,
    const float* __restrict__ c1b, const float* __restrict__ c2b,
    const float* __restrict__ f1b, const float* __restrict__ f2b,
    const float* __restrict__ b1g, const float* __restrict__ b1b,
    const float* __restrict__ b1m, const float* __restrict__ b1v,
    const float* __restrict__ b2g, const float* __restrict__ b2b,
    const float* __restrict__ b2m, const float* __restrict__ b2v,
    const float* __restrict__ b3g, const float* __restrict__ b3b,
    const float* __restrict__ b3m, const float* __restrict__ b3v,
    const float* __restrict__ b4g, const float* __restrict__ b4b,
    const float* __restrict__ b4m, const float* __restrict__ b4v,
    float* __restrict__ sw1, uint32_t* __restrict__ wp2,
    uint32_t* __restrict__ wpf1, uint32_t* __restrict__ wpf2,
    float* __restrict__ bnp1, float* __restrict__ bnp2,
    float* __restrict__ bnp3, float* __restrict__ bnp4) {
    int bid = blockIdx.x, t = threadIdx.x;
    if (bid < 1024) {
        // fc1 pack: wave W covers 512 consecutive elements of row o.
        int W = bid * 4 + (t >> 6), l = t & 63;
        int o = W >> 3, chunk = W & 7;
        const float* row = f1w + (size_t)o * 4096 + chunk * 512;
        int kwb = chunk * 16;
#pragma unroll
        for (int j = 0; j < 8; j++) {
            float vj = row[j * 64 + l];
            unsigned long long mk = __ballot(vj > 0.f);
            if (l == 0) {
                wpf1[(size_t)(kwb + 2 * j) * 512 + o] = (uint32_t)mk;
                wpf1[(size_t)(kwb + 2 * j + 1) * 512 + o] = (uint32_t)(mk >> 32);
            }
        }
    } else if (bid == 1024) {
        // conv2 pack: wp2[o*16+k]: k<9 = weight bits, k=9..15 = precomputed
        // border-correction constants {R0,R2,C0,C2,t0,t2,(t6|t8<<16)}.
        __shared__ uint32_t wloc[576];
        for (int i = t; i < 576; i += 256) {
            int o = i / 9, k = i - o * 9;
            uint32_t word = 0;
            for (int c = 0; c < 32; c++)
                if (c2w[(o * 32 + c) * 9 + k] > 0.f) word |= (1u << c);
            wloc[i] = word;
        }
        __syncthreads();
        for (int i = t; i < 1024; i += 256) {
            int o = i >> 4, k = i & 15;
            const uint32_t* wr = wloc + o * 9;
            uint32_t outv;
            if (k < 9) {
                outv = wr[k];
            } else {
                int tv[9];
#pragma unroll
                for (int j = 0; j < 9; j++) tv[j] = 32 - 2 * __popc(wr[j]);
                int v = 0;
                if (k == 9)  v = tv[0] + tv[1] + tv[2];            // R0
                if (k == 10) v = tv[6] + tv[7] + tv[8];            // R2
                if (k == 11) v = tv[0] + tv[3] + tv[6];            // C0
                if (k == 12) v = tv[2] + tv[5] + tv[8];            // C2
                if (k == 13) v = tv[0];                            // t0
                if (k == 14) v = tv[2];                            // t2
                if (k == 15)
                    v = (int)(((uint32_t)(uint16_t)tv[6]) |
                              ((uint32_t)(uint16_t)tv[8] << 16));  // t6|t8
                outv = (uint32_t)v;
            }
            wp2[i] = outv;
        }
        if (t < 64) {
            float inv = __fdiv_rn(b2g[t], __fsqrt_rn(b2v[t] + 1e-5f));
            float add = __fsub_rn(b2b[t], __fmul_rn(b2m[t], inv));
            bnp2[t * 4] = inv; bnp2[t * 4 + 1] = add;
            bnp2[t * 4 + 2] = c2b[t]; bnp2[t * 4 + 3] = 0.f;
        }
    } else if (bid == 1025) {
        // conv1 signed weights (stride-32 rows) + bn1 params.
        for (int i = t; i < 1024; i += 256) {
            int o = i >> 5, r = i & 31;
            sw1[i] = (r < 27) ? sgnf(c1w[o * 27 + r]) : 0.f;
        }
        if (t < 32) {
            float inv = __fdiv_rn(b1g[t], __fsqrt_rn(b1v[t] + 1e-5f));
            float add = __fsub_rn(b1b[t], __fmul_rn(b1m[t], inv));
            bnp1[t * 4] = inv; bnp1[t * 4 + 1] = add;
            bnp1[t * 4 + 2] = c1b[t]; bnp1[t * 4 + 3] = 0.f;
        }
    } else if (bid < 1042) {
        // fc2 pack: wpf2[k*256+o]
        int i = (bid - 1026) * 256 + t;       // 4096 = [16 k][256 o]
        int k = i >> 8, o = i & 255;
        const float* r = f2w + (size_t)o * 512 + k * 32;
        uint32_t word = 0;
#pragma unroll
        for (int j = 0; j < 32; j++)
            if (r[j] > 0.f) word |= (1u << j);
        wpf2[k * 256 + o] = word;
    } else {
        // bn3 + bn4 params (with fc biases folded in slot .z)
        for (int i = t; i < 512; i += 256) {
            float inv = __fdiv_rn(b3g[i], __fsqrt_rn(b3v[i] + 1e-5f));
            float add = __fsub_rn(b3b[i], __fmul_rn(b3m[i], inv));
            bnp3[i * 4] = inv; bnp3[i * 4 + 1] = add;
            bnp3[i * 4 + 2] = f1b[i]; bnp3[i * 4 + 3] = 0.f;
        }
        if (t < 256) {
            float inv = __fdiv_rn(b4g[t], __fsqrt_rn(b4v[t] + 1e-5f));
            float add = __fsub_rn(b4b[t], __fmul_rn(b4m[t], inv));
            bnp4[t * 4] = inv; bnp4[t * 4 + 1] = add;
            bnp4[t * 4 + 2] = f2b[t]; bnp4[t * 4 + 3] = 0.f;
        }
    }
}

// ---------------- k1: conv1 + pool + bn1 + sign-pack ----------------
// grid 2048, thread = 1 pooled pixel. Input staged via zero-padded LDS tile
// (coalesced fill), round-2 compute body (exact fmaf order, s_load weights).
__global__ __launch_bounds__(256) void k1_conv1(
    const float* __restrict__ x, const float* __restrict__ sw,
    const float* __restrict__ bnp, uint32_t* __restrict__ out) {
    int b = blockIdx.x, t = threadIdx.x;
    const int TS = 36;                       // tile row stride (words)
    __shared__ float tile[3 * 34 * TS];      // rows -1..32, cols -1..34 zero-padded
    for (int i = t; i < 3 * 34 * TS; i += 256) tile[i] = 0.f;
    __syncthreads();
#pragma unroll
    for (int q = 0; q < 3; q++) {            // 768 float4 = 3 per thread
        int idx = q * 256 + t;
        int c = idx >> 8, rem = idx & 255;
        int r = rem >> 3, c4 = rem & 7;
        float4 v = ((const float4*)(x + ((size_t)b * 3 + c) * 1024 + r * 32))[c4];
        float* dst = tile + c * (34 * TS) + (r + 1) * TS + c4 * 4 + 1;
        dst[0] = v.x; dst[1] = v.y; dst[2] = v.z; dst[3] = v.w;
    }
    __syncthreads();
    int py = t >> 4, px = t & 15;
    float in[48];
#pragma unroll
    for (int c = 0; c < 3; c++)
#pragma unroll
        for (int i = 0; i < 4; i++)
#pragma unroll
            for (int j = 0; j < 4; j++)
                in[c * 16 + i * 4 + j] =
                    tile[c * (34 * TS) + (2 * py + i) * TS + 2 * px + j];
    uint32_t word = 0;
#pragma unroll 2
    for (int o = 0; o < 32; o++) {
        const float* wo = sw + o * 32;           // uniform -> s_load
        float a00 = 0.f, a01 = 0.f, a10 = 0.f, a11 = 0.f;
#pragma unroll
        for (int c = 0; c < 3; c++)
#pragma unroll
            for (int ky = 0; ky < 3; ky++)
#pragma unroll
                for (int kx = 0; kx < 3; kx++) {
                    float wv = wo[c * 9 + ky * 3 + kx];
                    a00 = fmaf(in[c * 16 + ky * 4 + kx], wv, a00);
                    a01 = fmaf(in[c * 16 + ky * 4 + kx + 1], wv, a01);
                    a10 = fmaf(in[c * 16 + (ky + 1) * 4 + kx], wv, a10);
                    a11 = fmaf(in[c * 16 + (ky + 1) * 4 + kx + 1], wv, a11);
                }
        float4 p = ((const float4*)bnp)[o];      // uniform -> s_load
        float mx = fmaxf(fmaxf(a00, a01), fmaxf(a10, a11));
        float h = __fadd_rn(mx, p.z);
        float val = __fadd_rn(__fmul_rn(h, p.x), p.y);
        word |= (val > 0.f) ? (1u << o) : 0u;
    }
    out[(size_t)b * 256 + t] = word;
}

// ---------------- k3: conv2 xnor-popc + pool + bn2 + sign-pack ----------------
// 2 samples / block; per-channel: one s_load_dwordx16 row (weights + precomputed
// corrections), then 2 samples' worth of xor/popc per fetch.
__device__ __forceinline__ int conv2_mi(
    const uint32_t* val,
    uint32_t w0, uint32_t w1, uint32_t w2, uint32_t w3, uint32_t w4,
    uint32_t w5, uint32_t w6, uint32_t w7, uint32_t w8,
    int R0, int R2, int C0, int C2, int t0, int t2, int t6, int t8,
    bool top, bool bot, bool lef, bool rig,
    bool ctl, bool ctr, bool cbl, bool cbr) {
    int P00 = __popc(val[0] ^ w0) + __popc(val[1] ^ w1) + __popc(val[2] ^ w2) +
              __popc(val[4] ^ w3) + __popc(val[5] ^ w4) + __popc(val[6] ^ w5) +
              __popc(val[8] ^ w6) + __popc(val[9] ^ w7) + __popc(val[10] ^ w8);
    int P01 = __popc(val[1] ^ w0) + __popc(val[2] ^ w1) + __popc(val[3] ^ w2) +
              __popc(val[5] ^ w3) + __popc(val[6] ^ w4) + __popc(val[7] ^ w5) +
              __popc(val[9] ^ w6) + __popc(val[10] ^ w7) + __popc(val[11] ^ w8);
    int P10 = __popc(val[4] ^ w0) + __popc(val[5] ^ w1) + __popc(val[6] ^ w2) +
              __popc(val[8] ^ w3) + __popc(val[9] ^ w4) + __popc(val[10] ^ w5) +
              __popc(val[12] ^ w6) + __popc(val[13] ^ w7) + __popc(val[14] ^ w8);
    int P11 = __popc(val[5] ^ w0) + __popc(val[6] ^ w1) + __popc(val[7] ^ w2) +
              __popc(val[9] ^ w3) + __popc(val[10] ^ w4) + __popc(val[11] ^ w5) +
              __popc(val[13] ^ w6) + __popc(val[14] ^ w7) + __popc(val[15] ^ w8);
    int s00 = 288 - 2 * P00 - ((top ? R0 : 0) + (lef ? C0 : 0) - (ctl ? t0 : 0));
    int s01 = 288 - 2 * P01 - ((top ? R0 : 0) + (rig ? C2 : 0) - (ctr ? t2 : 0));
    int s10 = 288 - 2 * P10 - ((bot ? R2 : 0) + (lef ? C0 : 0) - (cbl ? t6 : 0));
    int s11 = 288 - 2 * P11 - ((bot ? R2 : 0) + (rig ? C2 : 0) - (cbr ? t8 : 0));
    return max(max(s00, s01), max(s10, s11));
}

__global__ __launch_bounds__(256) void k3_conv2(
    const uint32_t* __restrict__ in, const uint32_t* __restrict__ wp,
    const float* __restrict__ bnp, uint32_t* __restrict__ out) {
    int t = threadIdx.x;
    int b0 = blockIdx.x * 2;
    const int P = 19;
    __shared__ uint32_t tile[2][18 * 19];
    uint32_t* tf = &tile[0][0];
    for (int i = t; i < 2 * 18 * 19; i += 256) tf[i] = 0;
    __syncthreads();
    {
        int y = t >> 4, xx = t & 15;
#pragma unroll
        for (int s = 0; s < 2; s++)
            tile[s][(y + 1) * P + xx + 1] = in[(size_t)(b0 + s) * 256 + t];
    }
    __syncthreads();
    int wv = t >> 6, l = t & 63;
    int py = l >> 3, px = l & 7;
    uint32_t va[16], vb[16];
#pragma unroll
    for (int i = 0; i < 4; i++)
#pragma unroll
        for (int j = 0; j < 4; j++) {
            va[i * 4 + j] = tile[0][(2 * py + i) * P + 2 * px + j];
            vb[i * 4 + j] = tile[1][(2 * py + i) * P + 2 * px + j];
        }
    bool top = (py == 0), bot = (py == 7), lef = (px == 0), rig = (px == 7);
    bool ctl = top && lef, ctr = top && rig, cbl = bot && lef, cbr = bot && rig;
#pragma unroll 2
    for (int oi = 0; oi < 16; oi++) {
        int o = __builtin_amdgcn_readfirstlane(wv * 16 + oi);  // force SGPR
        const uint32_t* wo = wp + o * 16;
        uint32_t w0 = wo[0], w1 = wo[1], w2 = wo[2], w3 = wo[3], w4 = wo[4],
                 w5 = wo[5], w6 = wo[6], w7 = wo[7], w8 = wo[8];
        int R0 = (int)wo[9], R2 = (int)wo[10], C0 = (int)wo[11], C2 = (int)wo[12];
        int t0 = (int)wo[13], t2 = (int)wo[14];
        int pk = (int)wo[15];
        int t6 = (int)(short)(pk & 0xffff);
        int t8 = pk >> 16;
        float4 p = ((const float4*)bnp)[o];   // SGPR-indexed -> s_load
        int miA = conv2_mi(va, w0, w1, w2, w3, w4, w5, w6, w7, w8,
                           R0, R2, C0, C2, t0, t2, t6, t8,
                           top, bot, lef, rig, ctl, ctr, cbl, cbr);
        float hA = __fadd_rn((float)miA, p.z);
        float bvA = __fadd_rn(__fmul_rn(hA, p.x), p.y);
        unsigned long long mkA = __ballot(bvA > 0.f);
        int miB = conv2_mi(vb, w0, w1, w2, w3, w4, w5, w6, w7, w8,
                           R0, R2, C0, C2, t0, t2, t6, t8,
                           top, bot, lef, rig, ctl, ctr, cbl, cbr);
        float hB = __fadd_rn((float)miB, p.z);
        float bvB = __fadd_rn(__fmul_rn(hB, p.x), p.y);
        unsigned long long mkB = __ballot(bvB > 0.f);
        if (l == 0) {
            *(uint2*)(out + (size_t)b0 * 128 + 2 * o) =
                make_uint2((uint32_t)mkA, (uint32_t)(mkA >> 32));
            *(uint2*)(out + (size_t)(b0 + 1) * 128 + 2 * o) =
                make_uint2((uint32_t)mkB, (uint32_t)(mkB >> 32));
        }
    }
}

// ---------------- k4: fc1 xnor-popc + bn3 + sign-pack ----------------
__global__ __launch_bounds__(256) void k4_fc1(
    const uint32_t* __restrict__ in, const uint32_t* __restrict__ wp,
    const float* __restrict__ bnp, uint32_t* __restrict__ out) {
    int t = threadIdx.x;
    int half = blockIdx.x & 1, bg = blockIdx.x >> 1;
    int b0 = bg * 4;
    int wv = t >> 6, l = t & 63;
    int obase = half * 256 + wv * 64;
    int o = obase + l;
    float4 p = ((const float4*)bnp)[o];          // per-lane, coalesced
    const uint32_t* s0 = in + (size_t)b0 * 128;  // uniform -> s_load
    int a0 = 0, a1 = 0, a2 = 0, a3 = 0;
#pragma unroll 8
    for (int k = 0; k < 128; k++) {
        uint32_t w = wp[k * 512 + o];            // coalesced vector load
        a0 += __popc(w ^ s0[k]);
        a1 += __popc(w ^ s0[128 + k]);
        a2 += __popc(w ^ s0[256 + k]);
        a3 += __popc(w ^ s0[384 + k]);
    }
    int word_idx = obase >> 5;
    int accs[4] = {a0, a1, a2, a3};
#pragma unroll
    for (int nb = 0; nb < 4; nb++) {
        float h = __fadd_rn((float)(4096 - 2 * accs[nb]), p.z);
        float bv = __fadd_rn(__fmul_rn(h, p.x), p.y);
        unsigned long long mk = __ballot(bv > 0.f);
        if (l == 0) {
            out[(size_t)(b0 + nb) * 16 + word_idx] = (uint32_t)mk;
            out[(size_t)(b0 + nb) * 16 + word_idx + 1] = (uint32_t)(mk >> 32);
        }
    }
}

// ---------------- k56: fc2 + bn4 + clip + fc3 + log_softmax ----------------
// 4 samples per block (grid 512): wp reused 4x, softmax uses all 4 waves.
__global__ __launch_bounds__(256) void k56_fc23(
    const uint32_t* __restrict__ in, const uint32_t* __restrict__ wp,
    const float* __restrict__ bnp, const float* __restrict__ f3w,
    const float* __restrict__ f3b, float* __restrict__ out) {
    int b0 = blockIdx.x * 4, t = threadIdx.x;
    __shared__ uint32_t li[4][16];
    __shared__ float hbuf[4][256];
    if (t < 64) li[t >> 4][t & 15] = in[(size_t)(b0 + (t >> 4)) * 16 + (t & 15)];
    __syncthreads();
    int a0 = 0, a1 = 0, a2 = 0, a3 = 0;
#pragma unroll
    for (int k = 0; k < 16; k++) {
        uint32_t w = wp[k * 256 + t];
        a0 += __popc(w ^ li[0][k]);
        a1 += __popc(w ^ li[1][k]);
        a2 += __popc(w ^ li[2][k]);
        a3 += __popc(w ^ li[3][k]);
    }
    float4 p = ((const float4*)bnp)[t];
    int accs[4] = {a0, a1, a2, a3};
#pragma unroll
    for (int s = 0; s < 4; s++) {
        float h = __fadd_rn((float)(512 - 2 * accs[s]), p.z);
        float bv = __fadd_rn(__fmul_rn(h, p.x), p.y);
        hbuf[s][t] = fminf(1.f, fmaxf(-1.f, bv));
    }
    __syncthreads();
    int wv = t >> 6, l = t & 63;                 // wave wv -> sample b0+wv
    float4 hv = ((const float4*)(hbuf[wv]))[l];
    float logits[10];
#pragma unroll
    for (int j = 0; j < 10; j++) {
        const float4* wp4 = (const float4*)(f3w + j * 256);
        float4 w4 = wp4[l];
        float pp = hv.x * w4.x + hv.y * w4.y + hv.z * w4.z + hv.w * w4.w;
#pragma unroll
        for (int off = 32; off > 0; off >>= 1) pp += __shfl_xor(pp, off, 64);
        logits[j] = pp + f3b[j];
    }
    float mx = logits[0];
#pragma unroll
    for (int j = 1; j < 10; j++) mx = fmaxf(mx, logits[j]);
    float sum = 0.f;
#pragma unroll
    for (int j = 0; j < 10; j++) sum += expf(logits[j] - mx);
    float ls = mx + logf(sum);
    if (l < 10) out[(size_t)(b0 + wv) * 10 + l] = logits[l] - ls;
}

extern "C" void kernel_launch(void* const* d_in, const int* in_sizes, int n_in,
                              void* d_out, int out_size, void* d_ws, size_t ws_size,
                              hipStream_t stream) {
    (void)in_sizes; (void)n_in; (void)out_size; (void)ws_size;
    const float* x   = (const float*)d_in[0];
    const float* c1w = (const float*)d_in[1];
    const float* c1b = (const float*)d_in[2];
    const float* b1g = (const float*)d_in[3];
    const float* b1b = (const float*)d_in[4];
    const float* b1m = (const float*)d_in[5];
    const float* b1v = (const float*)d_in[6];
    const float* c2w = (const float*)d_in[7];
    const float* c2b = (const float*)d_in[8];
    const float* b2g = (const float*)d_in[9];
    const float* b2b = (const float*)d_in[10];
    const float* b2m = (const float*)d_in[11];
    const float* b2v = (const float*)d_in[12];
    const float* f1w = (const float*)d_in[13];
    const float* f1b = (const float*)d_in[14];
    const float* b3g = (const float*)d_in[15];
    const float* b3b = (const float*)d_in[16];
    const float* b3m = (const float*)d_in[17];
    const float* b3v = (const float*)d_in[18];
    const float* f2w = (const float*)d_in[19];
    const float* f2b = (const float*)d_in[20];
    const float* b4g = (const float*)d_in[21];
    const float* b4b = (const float*)d_in[22];
    const float* b4m = (const float*)d_in[23];
    const float* b4v = (const float*)d_in[24];
    const float* f3w = (const float*)d_in[25];
    const float* f3b = (const float*)d_in[26];
    float* out = (float*)d_out;

    uint8_t* ws = (uint8_t*)d_ws;
    uint32_t* ws1  = (uint32_t*)(ws + 0);         // [B,256] conv2 in bits  2 MB
    uint32_t* ws2  = (uint32_t*)(ws + 2097152);   // [B,128] fc1 in bits    1 MB
    uint32_t* ws3  = (uint32_t*)(ws + 3145728);   // [B,16]  fc2 in bits  128 KB
    float*    sw1  = (float*)   (ws + 3276800);   // [32,32] signed conv1 w
    uint32_t* wp2  = (uint32_t*)(ws + 3280896);   // [64,16] conv2 bits + corr
    uint32_t* wpf1 = (uint32_t*)(ws + 3284992);   // [128,512] fc1 bits^T
    uint32_t* wpf2 = (uint32_t*)(ws + 3547136);   // [16,256]  fc2 bits^T
    float*    bnp1 = (float*)   (ws + 3563520);   // [32]  {inv,add,bias,0}
    float*    bnp2 = (float*)   (ws + 3564032);   // [64]
    float*    bnp3 = (float*)   (ws + 3565056);   // [512]
    float*    bnp4 = (float*)   (ws + 3573248);   // [256]

    k0_pack<<<1043, 256, 0, stream>>>(c1w, c2w, f1w, f2w, c1b, c2b, f1b, f2b,
                                      b1g, b1b, b1m, b1v, b2g, b2b, b2m, b2v,
                                      b3g, b3b, b3m, b3v, b4g, b4b, b4m, b4v,
                                      sw1, wp2, wpf1, wpf2, bnp1, bnp2, bnp3, bnp4);
    k1_conv1<<<BSZ, 256, 0, stream>>>(x, sw1, bnp1, ws1);
    k3_conv2<<<BSZ / 2, 256, 0, stream>>>(ws1, wp2, bnp2, ws2);
    k4_fc1<<<1024, 256, 0, stream>>>(ws2, wpf1, bnp3, ws3);
    k56_fc23<<<BSZ / 4, 256, 0, stream>>>(ws3, wpf2, bnp4, f3w, f3b, out);
}